// Round 20
// baseline (298.319 us; speedup 1.0000x reference)
//
#include <hip/hip_runtime.h>

typedef unsigned short u16;
typedef unsigned int   u32;
typedef __bf16 bf16x8 __attribute__((ext_vector_type(8)));
typedef float  f32x16 __attribute__((ext_vector_type(16)));

__device__ __forceinline__ u16 f2bf(float f){
  u32 u = __float_as_uint(f);
  u32 r = (u + 0x7FFFu + ((u >> 16) & 1u)) >> 16;   // RNE
  return (u16)r;
}

// ===========================================================================
// TILED OPERAND LAYOUT (validated R8): tile = 32 rows x 16 k = 1KB,
// elem (row,k) -> tile (row>>5, k>>4), lane = (row&31)|(((k>>3)&1)<<5),
// byte = tile*1024 + lane*16 + (k&7)*2. Contiguous, lane-ordered.
//
// R19 post-mortem: B-register-direct hybrid regressed (B latency coupled
// into the barrier drain) -> gemm_rt REVERTED to R18 (B via LDS, 48us).
// R20: rowsum was the last 1-block/CU kernel (barrier drains unhidden).
// Split each 32-row group's K range across 2 blocks (grid 512, 16 chunks
// each, disjoint Ab writes) -> 2 blocks/CU overlap. Row sums become
// partials PS[2][8192]; ds_combine does rsqrt(p0+p1) (deterministic).
// ===========================================================================

// ---------------------------------------------------------------------------
// Pass 1: row sums (partial) + f32->bf16 + transpose to tiled layout.
// 512 blocks = 256 rowg x 2 k-halves; double-buffered, one barrier/chunk.
// ---------------------------------------------------------------------------
__global__ __launch_bounds__(1024) void rowsum_tileA(
    const float* __restrict__ A, u16* __restrict__ Ab, float* __restrict__ PS){
  __shared__ u16 lt[2][8192];            // 2 x 16 KB
  const int t = threadIdx.x;
  const int r = t >> 5, q = t & 31;      // row 0..31, 32 threads/row
  const int rg = blockIdx.x >> 1;
  const int kh = blockIdx.x & 1;
  const float* ar = A + ((size_t)rg * 32 + r) * 8192;
  float s = 0.f;
  for (int ci = 0; ci < 16; ++ci){
    const int ch = kh * 16 + ci;
    u16* lb = lt[ci & 1];
    #pragma unroll
    for (int j = 0; j < 2; ++j){
      const int c4 = ch * 64 + j * 32 + q;           // float4 col index
      float4 v = ((const float4*)ar)[c4];
      s += (v.x + v.y) + (v.z + v.w);
      const int cl = (j * 32 + q) * 4;               // local col 0..255
      const int tile = cl >> 4;
      const int tl   = (r | (((cl >> 3) & 1) << 5)) ^ (tile & 7);  // swizzled
      const int idx  = tile * 512 + tl * 8 + (cl & 7);
      ushort4 o;
      o.x = f2bf(v.x); o.y = f2bf(v.y); o.z = f2bf(v.z); o.w = f2bf(v.w);
      *(ushort4*)(lb + idx) = o;
    }
    __syncthreads();
    {
      const int tile = t >> 6, tl = t & 63;          // un-swizzle on read
      uint4 v = *(const uint4*)(lb + tile * 512 + (tl ^ (tile & 7)) * 8);
      uint4* dst = (uint4*)(Ab + ((size_t)rg * 512 + ch * 16) * 512);
      dst[t] = v;
    }
  }
  #pragma unroll
  for (int m = 16; m > 0; m >>= 1) s += __shfl_xor(s, m, 64);
  if (q == 0) PS[kh * 8192 + rg * 32 + r] = s;
}

__global__ __launch_bounds__(256) void ds_combine(
    const float* __restrict__ PS, float* __restrict__ ds){
  const int i = blockIdx.x * 256 + threadIdx.x;
  ds[i] = rsqrtf(PS[i] + PS[8192 + i]);
}

// ---------------------------------------------------------------------------
// prep_x: x f32 [8192][128] -> tiled bf16 Xt.
// ---------------------------------------------------------------------------
__global__ __launch_bounds__(1024) void prep_x(
    const float* __restrict__ x, u16* __restrict__ Xt){
  __shared__ u16 lt[4096];               // 8 tiles x 512 u16 = 8 KB
  const int t = threadIdx.x;
  const int r = t >> 5, q = t & 31;
  const int rg = blockIdx.x;
  float4 v = ((const float4*)(x + ((size_t)rg * 32 + r) * 128))[q];
  const int cl = q * 4;                  // local col 0..127
  const int tile = cl >> 4;              // 0..7
  const int tl   = (r | (((cl >> 3) & 1) << 5)) ^ (tile & 7);
  ushort4 o;
  o.x = f2bf(v.x); o.y = f2bf(v.y); o.z = f2bf(v.z); o.w = f2bf(v.w);
  *(ushort4*)(lt + tile * 512 + tl * 8 + (cl & 7)) = o;
  __syncthreads();
  if (t < 512){
    const int tile2 = t >> 6, tl2 = t & 63;
    uint4 w = *(const uint4*)(lt + tile2 * 512 + (tl2 ^ (tile2 & 7)) * 8);
    ((uint4*)(Xt + (size_t)rg * 4096))[t] = w;
  }
}

// ---------------------------------------------------------------------------
// prep_w: W1/W2/W3 f32 -> bf16 fragment tiles (fi = kt*(F/32) + ct).
// ---------------------------------------------------------------------------
__global__ __launch_bounds__(64) void prep_w(
    const float* __restrict__ W1, const float* __restrict__ W2,
    const float* __restrict__ W3, u16* __restrict__ W1t,
    u16* __restrict__ W2t, u16* __restrict__ W3t){
  const int b = blockIdx.x, l = threadIdx.x;
  const float* W; u16* Wt; int F, fi;
  if (b < 64)       { W = W1; Wt = W1t; F = 256; fi = b; }
  else if (b < 192) { W = W2; Wt = W2t; F = 256; fi = b - 64; }
  else              { W = W3; Wt = W3t; F = 128; fi = b - 192; }
  const int CT = F / 32;
  const int kt = fi / CT, ct = fi % CT;
  const int o  = ct * 32 + (l & 31);
  const int kb = kt * 16 + (l >> 5) * 8;
  union { u16 u[8]; uint4 v; } pk;
  #pragma unroll
  for (int e = 0; e < 8; ++e) pk.u[e] = f2bf(W[(size_t)(kb + e) * F + o]);
  *(uint4*)(Wt + (size_t)fi * 512 + l * 8) = pk.v;
}

// ---------------------------------------------------------------------------
// small_mfma<F,KT>: VT = (ds * H@W)^T tiled; register-direct; zero LDS.
// ---------------------------------------------------------------------------
template<int F, int KT>
__global__ __launch_bounds__(256) void small_mfma(
    const u16* __restrict__ Ht, const u16* __restrict__ Wt,
    const float* __restrict__ ds, u16* __restrict__ Vt){
  constexpr int CT = F / 128;           // col-tiles per wave (2 or 1)
  const int t = threadIdx.x, w = t >> 6, lane = t & 63;
  const int rowt = blockIdx.x;
  const u16* ha = Ht + ((size_t)rowt * KT) * 512 + lane * 8;
  const u16* wb = Wt + ((size_t)(w * CT)) * 512 + lane * 8;
  f32x16 acc[CT];
  #pragma unroll
  for (int ct = 0; ct < CT; ++ct)
    #pragma unroll
    for (int i = 0; i < 16; ++i) acc[ct][i] = 0.f;
  #pragma unroll
  for (int kt = 0; kt < KT; ++kt){
    bf16x8 a = *(const bf16x8*)(const void*)(ha + (size_t)kt * 512);
    #pragma unroll
    for (int ct = 0; ct < CT; ++ct){
      bf16x8 b = *(const bf16x8*)(const void*)(wb + (size_t)(kt * (F/32) + ct) * 512);
      acc[ct] = __builtin_amdgcn_mfma_f32_32x32x16_bf16(a, b, acc[ct], 0, 0, 0);
    }
  }
  const int rhi = (lane >> 5) << 2, cl = lane & 31;
  #pragma unroll
  for (int ct = 0; ct < CT; ++ct){
    const size_t obase = ((size_t)(w * CT + ct) * 512 + rowt * 2) * 512;
    #pragma unroll
    for (int r = 0; r < 16; ++r){
      const int rl = (r & 3) + ((r >> 2) << 3) + rhi;
      const int i  = rowt * 32 + rl;
      const u16 v = f2bf(acc[ct][r] * ds[i]);
      Vt[obase + (size_t)(rl >> 4) * 512 + (cl | (((rl >> 3) & 1) << 5)) * 8 + (rl & 7)] = v;
    }
  }
}

// ---------------------------------------------------------------------------
// F=256 big GEMM (R18 form, measured 48us): A+B via global_load_lds,
// double-buffered, register-tiled wave-K-split; H out tiled.
// ---------------------------------------------------------------------------
__global__ __launch_bounds__(256) void gemm_rt(
    const u16* __restrict__ Ab, const u16* __restrict__ Vt,
    const float* __restrict__ ds, u16* __restrict__ Hout){
  __shared__ u16 Ls[2][32 * 512];        // 2 x 32KB
  const int t = threadIdx.x, w = t >> 6, lane = t & 63;
  const int rowg = blockIdx.x & 127;
  const int colg = blockIdx.x >> 7;      // 0..3

  const u16* sP0 = Ab + ((size_t)(rowg * 2 + 0) * 512) * 512 + lane * 8;
  const u16* sP1 = Ab + ((size_t)(rowg * 2 + 1) * 512) * 512 + lane * 8;
  const u16* sP2 = Vt + ((size_t)(colg * 2 + 0) * 512) * 512 + lane * 8;
  const u16* sP3 = Vt + ((size_t)(colg * 2 + 1) * 512) * 512 + lane * 8;

  f32x16 a00, a01, a10, a11;
  #pragma unroll
  for (int i = 0; i < 16; ++i){ a00[i]=0.f; a01[i]=0.f; a10[i]=0.f; a11[i]=0.f; }

  auto stage = [&](int buf, int c){
    u16* L = &Ls[buf][0] + lane * 8;
    #pragma unroll
    for (int h = 0; h < 2; ++h){
      const int kt = c * 8 + h * 4 + w;
      const int sl = h * 4 + w;
      const size_t so = (size_t)kt * 512;
      __builtin_amdgcn_global_load_lds(
        (const __attribute__((address_space(1))) u32*)(sP0 + so),
        (__attribute__((address_space(3))) u32*)(L + (0  + sl) * 512), 16, 0, 0);
      __builtin_amdgcn_global_load_lds(
        (const __attribute__((address_space(1))) u32*)(sP1 + so),
        (__attribute__((address_space(3))) u32*)(L + (8  + sl) * 512), 16, 0, 0);
      __builtin_amdgcn_global_load_lds(
        (const __attribute__((address_space(1))) u32*)(sP2 + so),
        (__attribute__((address_space(3))) u32*)(L + (16 + sl) * 512), 16, 0, 0);
      __builtin_amdgcn_global_load_lds(
        (const __attribute__((address_space(1))) u32*)(sP3 + so),
        (__attribute__((address_space(3))) u32*)(L + (24 + sl) * 512), 16, 0, 0);
    }
  };
  auto compute = [&](int buf){
    const u16* L = &Ls[buf][0] + lane * 8;
    #pragma unroll
    for (int h = 0; h < 2; ++h){
      const int sl = h * 4 + w;
      bf16x8 fa0 = *(const bf16x8*)(const void*)(L + (0  + sl) * 512);
      bf16x8 fa1 = *(const bf16x8*)(const void*)(L + (8  + sl) * 512);
      bf16x8 fb0 = *(const bf16x8*)(const void*)(L + (16 + sl) * 512);
      bf16x8 fb1 = *(const bf16x8*)(const void*)(L + (24 + sl) * 512);
      a00 = __builtin_amdgcn_mfma_f32_32x32x16_bf16(fa0, fb0, a00, 0, 0, 0);
      a01 = __builtin_amdgcn_mfma_f32_32x32x16_bf16(fa0, fb1, a01, 0, 0, 0);
      a10 = __builtin_amdgcn_mfma_f32_32x32x16_bf16(fa1, fb0, a10, 0, 0, 0);
      a11 = __builtin_amdgcn_mfma_f32_32x32x16_bf16(fa1, fb1, a11, 0, 0, 0);
    }
  };

  stage(0, 0);
  __syncthreads();
  for (int c = 0; c < 64; ++c){
    if (c < 63) stage((c + 1) & 1, c + 1);
    compute(c & 1);
    __syncthreads();
  }

  // ---- tree-reduce the 4 wave-partials (reuse Ls as f32 scratch) ----
  float* Rf = (float*)(&Ls[0][0]);
  f32x16 aq[4];
  aq[0] = a00; aq[1] = a01; aq[2] = a10; aq[3] = a11;
  if (w >= 2){
    float* o = Rf + (w - 2) * 4096 + lane;
    #pragma unroll
    for (int q = 0; q < 4; ++q)
      #pragma unroll
      for (int r = 0; r < 16; ++r)
        o[(q * 16 + r) * 64] = aq[q][r];
  }
  __syncthreads();
  if (w < 2){
    const float* o = Rf + w * 4096 + lane;
    #pragma unroll
    for (int q = 0; q < 4; ++q)
      #pragma unroll
      for (int r = 0; r < 16; ++r)
        aq[q][r] += o[(q * 16 + r) * 64];
  }
  __syncthreads();
  if (w == 1){
    float* o = Rf + lane;
    #pragma unroll
    for (int q = 0; q < 4; ++q)
      #pragma unroll
      for (int r = 0; r < 16; ++r)
        o[(q * 16 + r) * 64] = aq[q][r];
  }
  __syncthreads();
  if (w == 0){
    const float* o = Rf + lane;
    const int rhi = (lane >> 5) << 2;
    const int cl  = lane & 31;
    #pragma unroll
    for (int q = 0; q < 4; ++q){
      const int rowtile = rowg * 2 + (q >> 1);
      const int ct16    = colg * 4 + (q & 1) * 2 + (cl >> 4);
      #pragma unroll
      for (int r = 0; r < 16; ++r){
        const int rl = (r & 3) + ((r >> 2) << 3) + rhi;
        const int row = rowg * 64 + (q >> 1) * 32 + rl;
        float v = aq[q][r] + o[(q * 16 + r) * 64];
        v *= ds[row];
        v = fmaxf(v, 0.f);
        Hout[((size_t)rowtile * 16 + ct16) * 512
             + (rl | (((cl >> 3) & 1) << 5)) * 8 + (cl & 7)] = f2bf(v);
      }
    }
  }
}

// ---------------------------------------------------------------------------
// F=128 big GEMM (R16 LDS structure): 32x64 tiles, f32 row-major out.
// ---------------------------------------------------------------------------
__global__ __launch_bounds__(256) void gemm_rt128(
    const u16* __restrict__ Ab, const u16* __restrict__ Vt,
    const float* __restrict__ ds, float* __restrict__ Fout){
  __shared__ u16 Ls[2][24 * 512];
  const int t = threadIdx.x, w = t >> 6, lane = t & 63;
  const int rowg = blockIdx.x & 255;
  const int colg = blockIdx.x >> 8;

  const u16* sA  = Ab + ((size_t)rowg * 512) * 512 + lane * 8;
  const u16* sB0 = Vt + ((size_t)(colg * 2 + 0) * 512) * 512 + lane * 8;
  const u16* sB1 = Vt + ((size_t)(colg * 2 + 1) * 512) * 512 + lane * 8;

  f32x16 p0, p1;
  #pragma unroll
  for (int i = 0; i < 16; ++i){ p0[i] = 0.f; p1[i] = 0.f; }

  auto stage = [&](int buf, int c){
    u16* L = &Ls[buf][0] + lane * 8;
    #pragma unroll
    for (int h = 0; h < 2; ++h){
      const int kt = c * 8 + h * 4 + w;
      const int sl = h * 4 + w;
      const size_t so = (size_t)kt * 512;
      __builtin_amdgcn_global_load_lds(
        (const __attribute__((address_space(1))) u32*)(sA + so),
        (__attribute__((address_space(3))) u32*)(L + (0  + sl) * 512), 16, 0, 0);
      __builtin_amdgcn_global_load_lds(
        (const __attribute__((address_space(1))) u32*)(sB0 + so),
        (__attribute__((address_space(3))) u32*)(L + (8  + sl) * 512), 16, 0, 0);
      __builtin_amdgcn_global_load_lds(
        (const __attribute__((address_space(1))) u32*)(sB1 + so),
        (__attribute__((address_space(3))) u32*)(L + (16 + sl) * 512), 16, 0, 0);
    }
  };
  auto compute = [&](int buf){
    const u16* L = &Ls[buf][0] + lane * 8;
    #pragma unroll
    for (int h = 0; h < 2; ++h){
      const int sl = h * 4 + w;
      bf16x8 fa  = *(const bf16x8*)(const void*)(L + (0  + sl) * 512);
      bf16x8 fb0 = *(const bf16x8*)(const void*)(L + (8  + sl) * 512);
      bf16x8 fb1 = *(const bf16x8*)(const void*)(L + (16 + sl) * 512);
      p0 = __builtin_amdgcn_mfma_f32_32x32x16_bf16(fa, fb0, p0, 0, 0, 0);
      p1 = __builtin_amdgcn_mfma_f32_32x32x16_bf16(fa, fb1, p1, 0, 0, 0);
    }
  };

  stage(0, 0);
  __syncthreads();
  for (int c = 0; c < 64; ++c){
    if (c < 63) stage((c + 1) & 1, c + 1);
    compute(c & 1);
    __syncthreads();
  }

  float* Rf = (float*)(&Ls[0][0]);
  f32x16 aq[2];
  aq[0] = p0; aq[1] = p1;
  if (w >= 2){
    float* o = Rf + (w - 2) * 2048 + lane;
    #pragma unroll
    for (int q = 0; q < 2; ++q)
      #pragma unroll
      for (int r = 0; r < 16; ++r)
        o[(q * 16 + r) * 64] = aq[q][r];
  }
  __syncthreads();
  if (w < 2){
    const float* o = Rf + w * 2048 + lane;
    #pragma unroll
    for (int q = 0; q < 2; ++q)
      #pragma unroll
      for (int r = 0; r < 16; ++r)
        aq[q][r] += o[(q * 16 + r) * 64];
  }
  __syncthreads();
  if (w == 1){
    float* o = Rf + lane;
    #pragma unroll
    for (int q = 0; q < 2; ++q)
      #pragma unroll
      for (int r = 0; r < 16; ++r)
        o[(q * 16 + r) * 64] = aq[q][r];
  }
  __syncthreads();
  if (w == 0){
    const float* o = Rf + lane;
    const int rhi = (lane >> 5) << 2;
    const int cl  = lane & 31;
    #pragma unroll
    for (int q = 0; q < 2; ++q){
      const int cbase = colg * 64 + q * 32;
      #pragma unroll
      for (int r = 0; r < 16; ++r){
        const int rl = (r & 3) + ((r >> 2) << 3) + rhi;
        const int row = rowg * 32 + rl;
        float v = aq[q][r] + o[(q * 16 + r) * 64];
        Fout[(size_t)row * 128 + cbase + cl] = v * ds[row];
      }
    }
  }
}

// ---------------------------------------------------------------------------
// Attention scores: sc[i] = tanh(Z[i,:] @ Wl^T + bl) @ q + b
// ---------------------------------------------------------------------------
__device__ __forceinline__ float tanh_fast(float x){
  x = fminf(fmaxf(x, -15.f), 15.f);
  float e = __expf(2.f * x);
  return (e - 1.f) / (e + 1.f);
}

__global__ __launch_bounds__(256) void attn_scores(
    const float* __restrict__ Z, const float* __restrict__ Wl,
    const float* __restrict__ bl, const float* __restrict__ q,
    const float* __restrict__ bsc, float* __restrict__ sc){
  __shared__ float wl[128 * 128];          // 64 KiB exactly, swizzled
  const int t = threadIdx.x, lane = t & 63, wave = t >> 6;
  for (int j = 0; j < 64; ++j){
    int idx = j * 256 + t;
    int o = idx >> 7, k = idx & 127;
    int c = k >> 2, e = k & 3;
    wl[o * 128 + (((c ^ (o & 31)) << 2) | e)] = Wl[idx];
  }
  __syncthreads();
  const float bl0 = bl[lane], bl1 = bl[lane + 64];
  const float q0  = q[lane],  q1  = q[lane + 64];
  const float bb  = bsc[0];
  const int r0 = blockIdx.x * 16;
  for (int rr = 0; rr < 4; ++rr){
    int r = r0 + wave * 4 + rr;
    float d0 = 0.f, d1 = 0.f;
    #pragma unroll
    for (int c = 0; c < 32; ++c){
      float4 zv = *(const float4*)(Z + (size_t)r * 128 + c * 4);
      float4 w0 = *(const float4*)&wl[ lane      * 128 + ((c ^ (lane & 31)) << 2)];
      float4 w1 = *(const float4*)&wl[(lane + 64)* 128 + ((c ^ (lane & 31)) << 2)];
      d0 += zv.x*w0.x + zv.y*w0.y + zv.z*w0.z + zv.w*w0.w;
      d1 += zv.x*w1.x + zv.y*w1.y + zv.z*w1.z + zv.w*w1.w;
    }
    float s = tanh_fast(d0 + bl0) * q0 + tanh_fast(d1 + bl1) * q1;
    #pragma unroll
    for (int off = 32; off > 0; off >>= 1) s += __shfl_down(s, off, 64);
    if (lane == 0) sc[r] = s + bb;
  }
}

__global__ __launch_bounds__(1024) void softmax_red(
    const float* __restrict__ sc, float* __restrict__ sred){
  const int t = threadIdx.x, lane = t & 63, wave = t >> 6;
  __shared__ float red[16];
  float m = -1e30f;
  for (int i = t; i < 8192; i += 1024) m = fmaxf(m, sc[i]);
  #pragma unroll
  for (int off = 32; off > 0; off >>= 1) m = fmaxf(m, __shfl_down(m, off, 64));
  if (lane == 0) red[wave] = m;
  __syncthreads();
  if (t == 0){
    float mm = red[0];
    for (int w = 1; w < 16; ++w) mm = fmaxf(mm, red[w]);
    red[0] = mm;
  }
  __syncthreads();
  const float bmax = red[0];
  __syncthreads();
  float s = 0.f;
  for (int i = t; i < 8192; i += 1024) s += __expf(sc[i] - bmax);
  #pragma unroll
  for (int off = 32; off > 0; off >>= 1) s += __shfl_down(s, off, 64);
  if (lane == 0) red[wave] = s;
  __syncthreads();
  if (t == 0){
    float ss = 0.f;
    for (int w = 0; w < 16; ++w) ss += red[w];
    sred[0] = bmax; sred[1] = ss;
  }
}

__global__ __launch_bounds__(256) void weighted_part(
    const float* __restrict__ sc, const float* __restrict__ sred,
    const float* __restrict__ Z, float* __restrict__ part){
  const int blk = blockIdx.x, t = threadIdx.x;
  const int o = t & 127, h = t >> 7;
  const float bmax = sred[0], inv = 1.f / sred[1];
  float acc = 0.f;
  const int i0 = blk * 128;
  for (int i = i0 + h; i < i0 + 128; i += 2){
    float w = __expf(sc[i] - bmax) * inv;
    acc += w * Z[(size_t)i * 128 + o];
  }
  __shared__ float l[256];
  l[t] = acc;
  __syncthreads();
  if (h == 0) part[blk * 128 + o] = l[o] + l[o + 128];
}

__global__ __launch_bounds__(128) void final_red(
    const float* __restrict__ part, float* __restrict__ out){
  const int o = threadIdx.x;
  float s = 0.f;
  for (int b = 0; b < 64; ++b) s += part[b * 128 + o];
  out[o] = s;
}

// ---------------------------------------------------------------------------
extern "C" void kernel_launch(void* const* d_in, const int* in_sizes, int n_in,
                              void* d_out, int out_size, void* d_ws, size_t ws_size,
                              hipStream_t stream){
  const float* x  = (const float*)d_in[0];
  const float* A  = (const float*)d_in[1];
  const float* W1 = (const float*)d_in[2];
  const float* W2 = (const float*)d_in[3];
  const float* W3 = (const float*)d_in[4];
  const float* Wl = (const float*)d_in[5];
  const float* bl = (const float*)d_in[6];
  const float* q  = (const float*)d_in[7];
  const float* b  = (const float*)d_in[8];
  float* out = (float*)d_out;
  char* ws = (char*)d_ws;

  u16*   AB   = (u16*)(ws);                      // 128 MiB, tiled
  float* DS   = (float*)(ws + 134217728);        // 32 KiB
  u16*   VT   = (u16*)(ws + 134250496);          // 4 MiB, tiled
  u16*   HB   = (u16*)(ws + 138444800);          // 4 MiB, tiled
  float* SC   = (float*)(ws + 142639104);        // 8192 f32 scores
  float* SP   = (float*)(ws + 142671872);        // 64*128 f32
  float* SRED = (float*)(ws + 142704640);        // {max, sumexp}
  u16*   W2T  = (u16*)(ws + 142705664);          // 128 KiB tiled W2
  u16*   W3T  = (u16*)(ws + 142836736);          // 64 KiB tiled W3
  u16*   W1T  = (u16*)(ws + 142902272);          // 64 KiB tiled W1
  u16*   XT   = (u16*)(ws + 142967808);          // 2 MiB tiled x
  float* PS   = (float*)(ws + 145064960);        // 64 KiB rowsum partials

  rowsum_tileA<<<512, 1024, 0, stream>>>(A, AB, PS);
  ds_combine<<<32, 256, 0, stream>>>(PS, DS);
  prep_x<<<256, 1024, 0, stream>>>(x, XT);
  prep_w<<<256, 64, 0, stream>>>(W1, W2, W3, W1T, W2T, W3T);
  // layer 1 (KT = 128/16 = 8)
  small_mfma<256, 8><<<256, 256, 0, stream>>>(XT, W1T, DS, VT);
  gemm_rt<<<512, 256, 0, stream>>>(AB, VT, DS, HB);
  // layer 2
  small_mfma<256, 16><<<256, 256, 0, stream>>>(HB, W2T, DS, VT);
  gemm_rt<<<512, 256, 0, stream>>>(AB, VT, DS, HB);
  // layer 3 -> z_context f32 straight into d_out
  small_mfma<128, 16><<<256, 256, 0, stream>>>(HB, W3T, DS, VT);
  gemm_rt128<<<512, 256, 0, stream>>>(AB, VT, DS, out);
  // attention pooling
  attn_scores<<<512, 256, 0, stream>>>(out, Wl, bl, q, b, SC);
  softmax_red<<<1, 1024, 0, stream>>>(SC, SRED);
  weighted_part<<<64, 256, 0, stream>>>(SC, SRED, out, SP);
  final_red<<<1, 128, 0, stream>>>(SP, out + 8192 * 128);
}

// Round 21
// 288.622 us; speedup vs baseline: 1.0336x; 1.0336x over previous
//
#include <hip/hip_runtime.h>

typedef unsigned short u16;
typedef unsigned int   u32;
typedef __bf16 bf16x8 __attribute__((ext_vector_type(8)));
typedef float  f32x16 __attribute__((ext_vector_type(16)));

__device__ __forceinline__ u16 f2bf(float f){
  u32 u = __float_as_uint(f);
  u32 r = (u + 0x7FFFu + ((u >> 16) & 1u)) >> 16;   // RNE
  return (u16)r;
}

// ===========================================================================
// FINAL (R21) = exact R18 configuration, the measured optimum (288.3 us).
// R19 (B-register-direct) and R20 (rowsum k-split) both regressed; reverted.
//
// TILED OPERAND LAYOUT (validated R8): tile = 32 rows x 16 k = 1KB,
// elem (row,k) -> tile (row>>5, k>>4), lane = (row&31)|(((k>>3)&1)<<5),
// byte = tile*1024 + lane*16 + (k&7)*2. Contiguous, lane-ordered: one tile
// is a single coalesced 1KB wave access for global loads, global stores,
// global_load_lds staging, and conflict-free ds_read_b128 fragments.
//
// Pipeline: rowsum+convert+tile A -> [small MFMA -> big LDS-staged MFMA] x3
// -> attention pooling. All matmuls on matrix cores; scaling by D^-1/2
// folded into epilogues; nadj never materialized.
// ===========================================================================

// ---------------------------------------------------------------------------
// Pass 1: row sums + f32->bf16 + transpose to tiled layout via LDS.
// Double-buffered, ONE barrier per chunk.
// ---------------------------------------------------------------------------
__global__ __launch_bounds__(1024) void rowsum_tileA(
    const float* __restrict__ A, u16* __restrict__ Ab, float* __restrict__ ds){
  __shared__ u16 lt[2][8192];            // 2 x 16 KB
  const int t = threadIdx.x;
  const int r = t >> 5, q = t & 31;      // row 0..31, 32 threads/row
  const int rg = blockIdx.x;
  const float* ar = A + ((size_t)rg * 32 + r) * 8192;
  float s = 0.f;
  for (int ch = 0; ch < 32; ++ch){
    u16* lb = lt[ch & 1];
    #pragma unroll
    for (int j = 0; j < 2; ++j){
      const int c4 = ch * 64 + j * 32 + q;           // float4 col index
      float4 v = ((const float4*)ar)[c4];
      s += (v.x + v.y) + (v.z + v.w);
      const int cl = (j * 32 + q) * 4;               // local col 0..255
      const int tile = cl >> 4;
      const int tl   = (r | (((cl >> 3) & 1) << 5)) ^ (tile & 7);  // swizzled
      const int idx  = tile * 512 + tl * 8 + (cl & 7);
      ushort4 o;
      o.x = f2bf(v.x); o.y = f2bf(v.y); o.z = f2bf(v.z); o.w = f2bf(v.w);
      *(ushort4*)(lb + idx) = o;
    }
    __syncthreads();
    {
      const int tile = t >> 6, tl = t & 63;          // un-swizzle on read
      uint4 v = *(const uint4*)(lb + tile * 512 + (tl ^ (tile & 7)) * 8);
      uint4* dst = (uint4*)(Ab + ((size_t)rg * 512 + ch * 16) * 512);
      dst[t] = v;
    }
  }
  #pragma unroll
  for (int m = 16; m > 0; m >>= 1) s += __shfl_xor(s, m, 64);
  if (q == 0) ds[rg * 32 + r] = rsqrtf(s);
}

// ---------------------------------------------------------------------------
// prep_x: x f32 [8192][128] -> tiled bf16 Xt.
// ---------------------------------------------------------------------------
__global__ __launch_bounds__(1024) void prep_x(
    const float* __restrict__ x, u16* __restrict__ Xt){
  __shared__ u16 lt[4096];               // 8 tiles x 512 u16 = 8 KB
  const int t = threadIdx.x;
  const int r = t >> 5, q = t & 31;
  const int rg = blockIdx.x;
  float4 v = ((const float4*)(x + ((size_t)rg * 32 + r) * 128))[q];
  const int cl = q * 4;                  // local col 0..127
  const int tile = cl >> 4;              // 0..7
  const int tl   = (r | (((cl >> 3) & 1) << 5)) ^ (tile & 7);
  ushort4 o;
  o.x = f2bf(v.x); o.y = f2bf(v.y); o.z = f2bf(v.z); o.w = f2bf(v.w);
  *(ushort4*)(lt + tile * 512 + tl * 8 + (cl & 7)) = o;
  __syncthreads();
  if (t < 512){
    const int tile2 = t >> 6, tl2 = t & 63;
    uint4 w = *(const uint4*)(lt + tile2 * 512 + (tl2 ^ (tile2 & 7)) * 8);
    ((uint4*)(Xt + (size_t)rg * 4096))[t] = w;
  }
}

// ---------------------------------------------------------------------------
// prep_w: W1/W2/W3 f32 -> bf16 fragment tiles (fi = kt*(F/32) + ct).
// ---------------------------------------------------------------------------
__global__ __launch_bounds__(64) void prep_w(
    const float* __restrict__ W1, const float* __restrict__ W2,
    const float* __restrict__ W3, u16* __restrict__ W1t,
    u16* __restrict__ W2t, u16* __restrict__ W3t){
  const int b = blockIdx.x, l = threadIdx.x;
  const float* W; u16* Wt; int F, fi;
  if (b < 64)       { W = W1; Wt = W1t; F = 256; fi = b; }
  else if (b < 192) { W = W2; Wt = W2t; F = 256; fi = b - 64; }
  else              { W = W3; Wt = W3t; F = 128; fi = b - 192; }
  const int CT = F / 32;
  const int kt = fi / CT, ct = fi % CT;
  const int o  = ct * 32 + (l & 31);
  const int kb = kt * 16 + (l >> 5) * 8;
  union { u16 u[8]; uint4 v; } pk;
  #pragma unroll
  for (int e = 0; e < 8; ++e) pk.u[e] = f2bf(W[(size_t)(kb + e) * F + o]);
  *(uint4*)(Wt + (size_t)fi * 512 + l * 8) = pk.v;
}

// ---------------------------------------------------------------------------
// small_mfma<F,KT>: VT = (ds * H@W)^T tiled; register-direct; zero LDS.
// ---------------------------------------------------------------------------
template<int F, int KT>
__global__ __launch_bounds__(256) void small_mfma(
    const u16* __restrict__ Ht, const u16* __restrict__ Wt,
    const float* __restrict__ ds, u16* __restrict__ Vt){
  constexpr int CT = F / 128;           // col-tiles per wave (2 or 1)
  const int t = threadIdx.x, w = t >> 6, lane = t & 63;
  const int rowt = blockIdx.x;
  const u16* ha = Ht + ((size_t)rowt * KT) * 512 + lane * 8;
  const u16* wb = Wt + ((size_t)(w * CT)) * 512 + lane * 8;
  f32x16 acc[CT];
  #pragma unroll
  for (int ct = 0; ct < CT; ++ct)
    #pragma unroll
    for (int i = 0; i < 16; ++i) acc[ct][i] = 0.f;
  #pragma unroll
  for (int kt = 0; kt < KT; ++kt){
    bf16x8 a = *(const bf16x8*)(const void*)(ha + (size_t)kt * 512);
    #pragma unroll
    for (int ct = 0; ct < CT; ++ct){
      bf16x8 b = *(const bf16x8*)(const void*)(wb + (size_t)(kt * (F/32) + ct) * 512);
      acc[ct] = __builtin_amdgcn_mfma_f32_32x32x16_bf16(a, b, acc[ct], 0, 0, 0);
    }
  }
  const int rhi = (lane >> 5) << 2, cl = lane & 31;
  #pragma unroll
  for (int ct = 0; ct < CT; ++ct){
    const size_t obase = ((size_t)(w * CT + ct) * 512 + rowt * 2) * 512;
    #pragma unroll
    for (int r = 0; r < 16; ++r){
      const int rl = (r & 3) + ((r >> 2) << 3) + rhi;
      const int i  = rowt * 32 + rl;
      const u16 v = f2bf(acc[ct][r] * ds[i]);
      Vt[obase + (size_t)(rl >> 4) * 512 + (cl | (((rl >> 3) & 1) << 5)) * 8 + (rl & 7)] = v;
    }
  }
}

// ---------------------------------------------------------------------------
// F=256 big GEMM (R14/R18 structure, measured 48us): A+B via global_load_lds,
// double-buffered, register-tiled wave-K-split; H out tiled.
// ---------------------------------------------------------------------------
__global__ __launch_bounds__(256) void gemm_rt(
    const u16* __restrict__ Ab, const u16* __restrict__ Vt,
    const float* __restrict__ ds, u16* __restrict__ Hout){
  __shared__ u16 Ls[2][32 * 512];        // 2 x 32KB
  const int t = threadIdx.x, w = t >> 6, lane = t & 63;
  const int rowg = blockIdx.x & 127;
  const int colg = blockIdx.x >> 7;      // 0..3

  const u16* sP0 = Ab + ((size_t)(rowg * 2 + 0) * 512) * 512 + lane * 8;
  const u16* sP1 = Ab + ((size_t)(rowg * 2 + 1) * 512) * 512 + lane * 8;
  const u16* sP2 = Vt + ((size_t)(colg * 2 + 0) * 512) * 512 + lane * 8;
  const u16* sP3 = Vt + ((size_t)(colg * 2 + 1) * 512) * 512 + lane * 8;

  f32x16 a00, a01, a10, a11;
  #pragma unroll
  for (int i = 0; i < 16; ++i){ a00[i]=0.f; a01[i]=0.f; a10[i]=0.f; a11[i]=0.f; }

  auto stage = [&](int buf, int c){
    u16* L = &Ls[buf][0] + lane * 8;
    #pragma unroll
    for (int h = 0; h < 2; ++h){
      const int kt = c * 8 + h * 4 + w;
      const int sl = h * 4 + w;
      const size_t so = (size_t)kt * 512;
      __builtin_amdgcn_global_load_lds(
        (const __attribute__((address_space(1))) u32*)(sP0 + so),
        (__attribute__((address_space(3))) u32*)(L + (0  + sl) * 512), 16, 0, 0);
      __builtin_amdgcn_global_load_lds(
        (const __attribute__((address_space(1))) u32*)(sP1 + so),
        (__attribute__((address_space(3))) u32*)(L + (8  + sl) * 512), 16, 0, 0);
      __builtin_amdgcn_global_load_lds(
        (const __attribute__((address_space(1))) u32*)(sP2 + so),
        (__attribute__((address_space(3))) u32*)(L + (16 + sl) * 512), 16, 0, 0);
      __builtin_amdgcn_global_load_lds(
        (const __attribute__((address_space(1))) u32*)(sP3 + so),
        (__attribute__((address_space(3))) u32*)(L + (24 + sl) * 512), 16, 0, 0);
    }
  };
  auto compute = [&](int buf){
    const u16* L = &Ls[buf][0] + lane * 8;
    #pragma unroll
    for (int h = 0; h < 2; ++h){
      const int sl = h * 4 + w;
      bf16x8 fa0 = *(const bf16x8*)(const void*)(L + (0  + sl) * 512);
      bf16x8 fa1 = *(const bf16x8*)(const void*)(L + (8  + sl) * 512);
      bf16x8 fb0 = *(const bf16x8*)(const void*)(L + (16 + sl) * 512);
      bf16x8 fb1 = *(const bf16x8*)(const void*)(L + (24 + sl) * 512);
      a00 = __builtin_amdgcn_mfma_f32_32x32x16_bf16(fa0, fb0, a00, 0, 0, 0);
      a01 = __builtin_amdgcn_mfma_f32_32x32x16_bf16(fa0, fb1, a01, 0, 0, 0);
      a10 = __builtin_amdgcn_mfma_f32_32x32x16_bf16(fa1, fb0, a10, 0, 0, 0);
      a11 = __builtin_amdgcn_mfma_f32_32x32x16_bf16(fa1, fb1, a11, 0, 0, 0);
    }
  };

  stage(0, 0);
  __syncthreads();
  for (int c = 0; c < 64; ++c){
    if (c < 63) stage((c + 1) & 1, c + 1);
    compute(c & 1);
    __syncthreads();
  }

  // ---- tree-reduce the 4 wave-partials (reuse Ls as f32 scratch) ----
  float* Rf = (float*)(&Ls[0][0]);
  f32x16 aq[4];
  aq[0] = a00; aq[1] = a01; aq[2] = a10; aq[3] = a11;
  if (w >= 2){
    float* o = Rf + (w - 2) * 4096 + lane;
    #pragma unroll
    for (int q = 0; q < 4; ++q)
      #pragma unroll
      for (int r = 0; r < 16; ++r)
        o[(q * 16 + r) * 64] = aq[q][r];
  }
  __syncthreads();
  if (w < 2){
    const float* o = Rf + w * 4096 + lane;
    #pragma unroll
    for (int q = 0; q < 4; ++q)
      #pragma unroll
      for (int r = 0; r < 16; ++r)
        aq[q][r] += o[(q * 16 + r) * 64];
  }
  __syncthreads();
  if (w == 1){
    float* o = Rf + lane;
    #pragma unroll
    for (int q = 0; q < 4; ++q)
      #pragma unroll
      for (int r = 0; r < 16; ++r)
        o[(q * 16 + r) * 64] = aq[q][r];
  }
  __syncthreads();
  if (w == 0){
    const float* o = Rf + lane;
    const int rhi = (lane >> 5) << 2;
    const int cl  = lane & 31;
    #pragma unroll
    for (int q = 0; q < 4; ++q){
      const int rowtile = rowg * 2 + (q >> 1);
      const int ct16    = colg * 4 + (q & 1) * 2 + (cl >> 4);
      #pragma unroll
      for (int r = 0; r < 16; ++r){
        const int rl = (r & 3) + ((r >> 2) << 3) + rhi;
        const int row = rowg * 64 + (q >> 1) * 32 + rl;
        float v = aq[q][r] + o[(q * 16 + r) * 64];
        v *= ds[row];
        v = fmaxf(v, 0.f);
        Hout[((size_t)rowtile * 16 + ct16) * 512
             + (rl | (((cl >> 3) & 1) << 5)) * 8 + (cl & 7)] = f2bf(v);
      }
    }
  }
}

// ---------------------------------------------------------------------------
// F=128 big GEMM (R16 LDS structure): 32x64 tiles, f32 row-major out.
// ---------------------------------------------------------------------------
__global__ __launch_bounds__(256) void gemm_rt128(
    const u16* __restrict__ Ab, const u16* __restrict__ Vt,
    const float* __restrict__ ds, float* __restrict__ Fout){
  __shared__ u16 Ls[2][24 * 512];
  const int t = threadIdx.x, w = t >> 6, lane = t & 63;
  const int rowg = blockIdx.x & 255;
  const int colg = blockIdx.x >> 8;

  const u16* sA  = Ab + ((size_t)rowg * 512) * 512 + lane * 8;
  const u16* sB0 = Vt + ((size_t)(colg * 2 + 0) * 512) * 512 + lane * 8;
  const u16* sB1 = Vt + ((size_t)(colg * 2 + 1) * 512) * 512 + lane * 8;

  f32x16 p0, p1;
  #pragma unroll
  for (int i = 0; i < 16; ++i){ p0[i] = 0.f; p1[i] = 0.f; }

  auto stage = [&](int buf, int c){
    u16* L = &Ls[buf][0] + lane * 8;
    #pragma unroll
    for (int h = 0; h < 2; ++h){
      const int kt = c * 8 + h * 4 + w;
      const int sl = h * 4 + w;
      const size_t so = (size_t)kt * 512;
      __builtin_amdgcn_global_load_lds(
        (const __attribute__((address_space(1))) u32*)(sA + so),
        (__attribute__((address_space(3))) u32*)(L + (0  + sl) * 512), 16, 0, 0);
      __builtin_amdgcn_global_load_lds(
        (const __attribute__((address_space(1))) u32*)(sB0 + so),
        (__attribute__((address_space(3))) u32*)(L + (8  + sl) * 512), 16, 0, 0);
      __builtin_amdgcn_global_load_lds(
        (const __attribute__((address_space(1))) u32*)(sB1 + so),
        (__attribute__((address_space(3))) u32*)(L + (16 + sl) * 512), 16, 0, 0);
    }
  };
  auto compute = [&](int buf){
    const u16* L = &Ls[buf][0] + lane * 8;
    #pragma unroll
    for (int h = 0; h < 2; ++h){
      const int sl = h * 4 + w;
      bf16x8 fa  = *(const bf16x8*)(const void*)(L + (0  + sl) * 512);
      bf16x8 fb0 = *(const bf16x8*)(const void*)(L + (8  + sl) * 512);
      bf16x8 fb1 = *(const bf16x8*)(const void*)(L + (16 + sl) * 512);
      p0 = __builtin_amdgcn_mfma_f32_32x32x16_bf16(fa, fb0, p0, 0, 0, 0);
      p1 = __builtin_amdgcn_mfma_f32_32x32x16_bf16(fa, fb1, p1, 0, 0, 0);
    }
  };

  stage(0, 0);
  __syncthreads();
  for (int c = 0; c < 64; ++c){
    if (c < 63) stage((c + 1) & 1, c + 1);
    compute(c & 1);
    __syncthreads();
  }

  float* Rf = (float*)(&Ls[0][0]);
  f32x16 aq[2];
  aq[0] = p0; aq[1] = p1;
  if (w >= 2){
    float* o = Rf + (w - 2) * 2048 + lane;
    #pragma unroll
    for (int q = 0; q < 2; ++q)
      #pragma unroll
      for (int r = 0; r < 16; ++r)
        o[(q * 16 + r) * 64] = aq[q][r];
  }
  __syncthreads();
  if (w < 2){
    const float* o = Rf + w * 2048 + lane;
    #pragma unroll
    for (int q = 0; q < 2; ++q)
      #pragma unroll
      for (int r = 0; r < 16; ++r)
        aq[q][r] += o[(q * 16 + r) * 64];
  }
  __syncthreads();
  if (w == 1){
    float* o = Rf + lane;
    #pragma unroll
    for (int q = 0; q < 2; ++q)
      #pragma unroll
      for (int r = 0; r < 16; ++r)
        o[(q * 16 + r) * 64] = aq[q][r];
  }
  __syncthreads();
  if (w == 0){
    const float* o = Rf + lane;
    const int rhi = (lane >> 5) << 2;
    const int cl  = lane & 31;
    #pragma unroll
    for (int q = 0; q < 2; ++q){
      const int cbase = colg * 64 + q * 32;
      #pragma unroll
      for (int r = 0; r < 16; ++r){
        const int rl = (r & 3) + ((r >> 2) << 3) + rhi;
        const int row = rowg * 32 + rl;
        float v = aq[q][r] + o[(q * 16 + r) * 64];
        Fout[(size_t)row * 128 + cbase + cl] = v * ds[row];
      }
    }
  }
}

// ---------------------------------------------------------------------------
// Attention scores: sc[i] = tanh(Z[i,:] @ Wl^T + bl) @ q + b
// ---------------------------------------------------------------------------
__device__ __forceinline__ float tanh_fast(float x){
  x = fminf(fmaxf(x, -15.f), 15.f);
  float e = __expf(2.f * x);
  return (e - 1.f) / (e + 1.f);
}

__global__ __launch_bounds__(256) void attn_scores(
    const float* __restrict__ Z, const float* __restrict__ Wl,
    const float* __restrict__ bl, const float* __restrict__ q,
    const float* __restrict__ bsc, float* __restrict__ sc){
  __shared__ float wl[128 * 128];          // 64 KiB exactly, swizzled
  const int t = threadIdx.x, lane = t & 63, wave = t >> 6;
  for (int j = 0; j < 64; ++j){
    int idx = j * 256 + t;
    int o = idx >> 7, k = idx & 127;
    int c = k >> 2, e = k & 3;
    wl[o * 128 + (((c ^ (o & 31)) << 2) | e)] = Wl[idx];
  }
  __syncthreads();
  const float bl0 = bl[lane], bl1 = bl[lane + 64];
  const float q0  = q[lane],  q1  = q[lane + 64];
  const float bb  = bsc[0];
  const int r0 = blockIdx.x * 16;
  for (int rr = 0; rr < 4; ++rr){
    int r = r0 + wave * 4 + rr;
    float d0 = 0.f, d1 = 0.f;
    #pragma unroll
    for (int c = 0; c < 32; ++c){
      float4 zv = *(const float4*)(Z + (size_t)r * 128 + c * 4);
      float4 w0 = *(const float4*)&wl[ lane      * 128 + ((c ^ (lane & 31)) << 2)];
      float4 w1 = *(const float4*)&wl[(lane + 64)* 128 + ((c ^ (lane & 31)) << 2)];
      d0 += zv.x*w0.x + zv.y*w0.y + zv.z*w0.z + zv.w*w0.w;
      d1 += zv.x*w1.x + zv.y*w1.y + zv.z*w1.z + zv.w*w1.w;
    }
    float s = tanh_fast(d0 + bl0) * q0 + tanh_fast(d1 + bl1) * q1;
    #pragma unroll
    for (int off = 32; off > 0; off >>= 1) s += __shfl_down(s, off, 64);
    if (lane == 0) sc[r] = s + bb;
  }
}

__global__ __launch_bounds__(1024) void softmax_red(
    const float* __restrict__ sc, float* __restrict__ sred){
  const int t = threadIdx.x, lane = t & 63, wave = t >> 6;
  __shared__ float red[16];
  float m = -1e30f;
  for (int i = t; i < 8192; i += 1024) m = fmaxf(m, sc[i]);
  #pragma unroll
  for (int off = 32; off > 0; off >>= 1) m = fmaxf(m, __shfl_down(m, off, 64));
  if (lane == 0) red[wave] = m;
  __syncthreads();
  if (t == 0){
    float mm = red[0];
    for (int w = 1; w < 16; ++w) mm = fmaxf(mm, red[w]);
    red[0] = mm;
  }
  __syncthreads();
  const float bmax = red[0];
  __syncthreads();
  float s = 0.f;
  for (int i = t; i < 8192; i += 1024) s += __expf(sc[i] - bmax);
  #pragma unroll
  for (int off = 32; off > 0; off >>= 1) s += __shfl_down(s, off, 64);
  if (lane == 0) red[wave] = s;
  __syncthreads();
  if (t == 0){
    float ss = 0.f;
    for (int w = 0; w < 16; ++w) ss += red[w];
    sred[0] = bmax; sred[1] = ss;
  }
}

__global__ __launch_bounds__(256) void weighted_part(
    const float* __restrict__ sc, const float* __restrict__ sred,
    const float* __restrict__ Z, float* __restrict__ part){
  const int blk = blockIdx.x, t = threadIdx.x;
  const int o = t & 127, h = t >> 7;
  const float bmax = sred[0], inv = 1.f / sred[1];
  float acc = 0.f;
  const int i0 = blk * 128;
  for (int i = i0 + h; i < i0 + 128; i += 2){
    float w = __expf(sc[i] - bmax) * inv;
    acc += w * Z[(size_t)i * 128 + o];
  }
  __shared__ float l[256];
  l[t] = acc;
  __syncthreads();
  if (h == 0) part[blk * 128 + o] = l[o] + l[o + 128];
}

__global__ __launch_bounds__(128) void final_red(
    const float* __restrict__ part, float* __restrict__ out){
  const int o = threadIdx.x;
  float s = 0.f;
  for (int b = 0; b < 64; ++b) s += part[b * 128 + o];
  out[o] = s;
}

// ---------------------------------------------------------------------------
extern "C" void kernel_launch(void* const* d_in, const int* in_sizes, int n_in,
                              void* d_out, int out_size, void* d_ws, size_t ws_size,
                              hipStream_t stream){
  const float* x  = (const float*)d_in[0];
  const float* A  = (const float*)d_in[1];
  const float* W1 = (const float*)d_in[2];
  const float* W2 = (const float*)d_in[3];
  const float* W3 = (const float*)d_in[4];
  const float* Wl = (const float*)d_in[5];
  const float* bl = (const float*)d_in[6];
  const float* q  = (const float*)d_in[7];
  const float* b  = (const float*)d_in[8];
  float* out = (float*)d_out;
  char* ws = (char*)d_ws;

  u16*   AB   = (u16*)(ws);                      // 128 MiB, tiled
  float* DS   = (float*)(ws + 134217728);        // 32 KiB
  u16*   VT   = (u16*)(ws + 134250496);          // 4 MiB, tiled
  u16*   HB   = (u16*)(ws + 138444800);          // 4 MiB, tiled
  float* SC   = (float*)(ws + 142639104);        // 8192 f32 scores
  float* SP   = (float*)(ws + 142671872);        // 64*128 f32
  float* SRED = (float*)(ws + 142704640);        // {max, sumexp}
  u16*   W2T  = (u16*)(ws + 142705664);          // 128 KiB tiled W2
  u16*   W3T  = (u16*)(ws + 142836736);          // 64 KiB tiled W3
  u16*   W1T  = (u16*)(ws + 142902272);          // 64 KiB tiled W1
  u16*   XT   = (u16*)(ws + 142967808);          // 2 MiB tiled x

  rowsum_tileA<<<256, 1024, 0, stream>>>(A, AB, DS);
  prep_x<<<256, 1024, 0, stream>>>(x, XT);
  prep_w<<<256, 64, 0, stream>>>(W1, W2, W3, W1T, W2T, W3T);
  // layer 1 (KT = 128/16 = 8)
  small_mfma<256, 8><<<256, 256, 0, stream>>>(XT, W1T, DS, VT);
  gemm_rt<<<512, 256, 0, stream>>>(AB, VT, DS, HB);
  // layer 2
  small_mfma<256, 16><<<256, 256, 0, stream>>>(HB, W2T, DS, VT);
  gemm_rt<<<512, 256, 0, stream>>>(AB, VT, DS, HB);
  // layer 3 -> z_context f32 straight into d_out
  small_mfma<128, 16><<<256, 256, 0, stream>>>(HB, W3T, DS, VT);
  gemm_rt128<<<512, 256, 0, stream>>>(AB, VT, DS, out);
  // attention pooling
  attn_scores<<<512, 256, 0, stream>>>(out, Wl, bl, q, b, SC);
  softmax_red<<<1, 1024, 0, stream>>>(SC, SRED);
  weighted_part<<<64, 256, 0, stream>>>(SC, SRED, out, SP);
  final_red<<<1, 128, 0, stream>>>(SP, out + 8192 * 128);
}